// Round 1
// baseline (399.329 us; speedup 1.0000x reference)
//
#include <hip/hip_runtime.h>
#include <cstddef>

#define H_   512
#define W_   512
#define NIMG 96            // 32 batch * 3 channels
#define PD_  16            // pad = KS/2
#define TX   256           // output cols per block (== blockDim.x)
#define TY   128           // output rows per block
#define XD   18            // x-row ring depth (>=17 for 1-barrier safety)
#define NPC  287           // padded cols needed per strip: TX + 31

// one DPP scan step: x += dpp_shifted(x); masked-off rows contribute 0
template <int CTRL, int RMASK>
__device__ __forceinline__ float dpp_add(float x) {
    int t = __builtin_amdgcn_update_dpp(0, __float_as_int(x), CTRL, RMASK, 0xf, true);
    return x + __int_as_float(t);
}

// wave64 inclusive prefix sum, pure VALU (6 instrs): row_shr 1/2/4/8,
// row_bcast:15 -> rows 1,3, row_bcast:31 -> rows 2,3  (classic gfx9 scan)
__device__ __forceinline__ float wave_incl_scan(float x) {
    x = dpp_add<0x111, 0xf>(x);
    x = dpp_add<0x112, 0xf>(x);
    x = dpp_add<0x114, 0xf>(x);
    x = dpp_add<0x118, 0xf>(x);
    x = dpp_add<0x142, 0xa>(x);
    x = dpp_add<0x143, 0xc>(x);
    return x;
}

__global__ void __launch_bounds__(256)
localnorm_kernel(const float* __restrict__ xin, float* __restrict__ out)
{
    const int tid  = threadIdx.x;
    const int lane = tid & 63;
    const int wv   = tid >> 6;

    const int x0   = blockIdx.x * TX;   // strip: 0 or 256
    const int row0 = blockIdx.y * TY;   // band: 0,128,256,384
    const int img  = blockIdx.z;        // 0..95

    const float* __restrict__ src = xin + (size_t)img * (H_ * W_);
    float* __restrict__ dst = out + (size_t)img * (H_ * W_) + (size_t)row0 * W_ + x0;

    // per-thread reflected column indices (row-invariant)
    int pc = x0 + tid - PD_;                       // padded col x0+tid -> orig col
    const int oc_main = (pc < 0) ? -pc : ((pc > W_ - 1) ? 2 * (W_ - 1) - pc : pc);
    int pct = x0 + TX + tid - PD_;                 // tail cols (lanes 0..30 of wave 0)
    const int oc_tail = (pct > W_ - 1) ? 2 * (W_ - 1) - pct : pct;
    const bool is_tail = (tid < NPC - TX);         // tid < 31

    __shared__ float  xbuf[XD][NPC + 1];           // raw x ring (needed for epilogue)
    __shared__ float2 Sp[2][NPC + 2];              // wave-local exclusive prefixes {sum, sumsq}
    __shared__ float2 wtot[2][4];                  // per-wave totals

    // 32-deep rolling history of horizontal sums, kept in registers via unroll
    float histg[32], histq[32];
#pragma unroll
    for (int k = 0; k < 32; ++k) { histg[k] = 0.f; histq[k] = 0.f; }
    float vg = 0.f, vq = 0.f;                      // vertical rolling sums (32 rows)

    auto do_iter = [&](int p, int kslot, bool doOut, int i) {
        // ---- load entering padded row p (absolute padded row = row0 + p) ----
        int rr = row0 + p - PD_;
        rr = (rr < 0) ? -rr : ((rr > H_ - 1) ? 2 * (H_ - 1) - rr : rr);
        const float* __restrict__ rowp = src + rr * W_;
        float g  = rowp[oc_main];
        float gt = is_tail ? rowp[oc_tail] : 0.f;

        const int slot = p % XD;
        const int par  = p & 1;
        xbuf[slot][tid] = g;
        if (is_tail) xbuf[slot][TX + tid] = gt;

        float q  = g * g;
        float qt = gt * gt;

        // ---- horizontal prefix scans (value and square) ----
        float sg = wave_incl_scan(g);
        float sq = wave_incl_scan(q);
        if (lane == 63) wtot[par][wv] = make_float2(sg, sq);
        Sp[par][tid] = make_float2(sg - g, sq - q);        // wave-local exclusive
        if (wv == 0) {                                     // tail: 31 extra cols, wave 0
            float stg = wave_incl_scan(gt);
            float stq = wave_incl_scan(qt);
            if (is_tail) Sp[par][TX + tid] = make_float2(stg - gt, stq - qt);
            if (tid == 30) Sp[par][NPC] = make_float2(stg, stq);  // S[287] local
        }
        __syncthreads();

        // hsum[j] = S[j+32] - S[j]; cross-wave fixup = own wave total iff lane>=32
        float2 wt  = wtot[par][wv];
        float2 slo = Sp[par][tid];
        float2 shi = Sp[par][tid + 32];
        float hg = shi.x - slo.x + ((lane >= 32) ? wt.x : 0.f);
        float hq = shi.y - slo.y + ((lane >= 32) ? wt.y : 0.f);

        // ---- vertical rolling window update (register history, static kslot) ----
        vg += hg - histg[kslot]; histg[kslot] = hg;
        vq += hq - histq[kslot]; histq[kslot] = hq;

        if (doOut) {
            // x value for output row i = padded row i+16, stored 15 iters ago
            float xv = xbuf[(p - 15) % XD][tid + PD_];
            float mg = vg * (1.f / 1024.f);
            float mq = vq * (1.f / 1024.f);
            float var = fabsf(mq - mg * mg);
            float sd = sqrtf(var) + 1e-10f;
            float r = __fdividef(xv - mg, sd);
            r = fminf(fmaxf(r, -6.f), 6.f);
            dst[i * W_ + tid] = r;
        }
    };

    // prologue: fill window with padded rows 0..30
#pragma unroll
    for (int p = 0; p < 31; ++p) do_iter(p, p, false, 0);

    // main: output rows i = 0..TY-1; entering padded row p = i+31
    for (int ii = 0; ii < TY; ii += 32) {
#pragma unroll
        for (int kk = 0; kk < 32; ++kk) {
            do_iter(ii + kk + 31, (kk + 31) & 31, true, ii + kk);
        }
    }
}

extern "C" void kernel_launch(void* const* d_in, const int* in_sizes, int n_in,
                              void* d_out, int out_size, void* d_ws, size_t ws_size,
                              hipStream_t stream) {
    (void)in_sizes; (void)n_in; (void)d_ws; (void)ws_size; (void)out_size;
    const float* x = (const float*)d_in[0];
    float* o = (float*)d_out;
    dim3 grid(W_ / TX, H_ / TY, NIMG);   // 2 x 4 x 96 = 768 blocks
    localnorm_kernel<<<grid, dim3(256), 0, stream>>>(x, o);
}

// Round 3
// 275.294 us; speedup vs baseline: 1.4506x; 1.4506x over previous
//
#include <hip/hip_runtime.h>
#include <cstddef>

#define H_    512
#define W_    512
#define NIMG  96           // 32 batch * 3 channels
#define PD_   16           // pad = KS/2
#define TY    128          // output rows per band
#define NROWS (TY + 31)    // 159 padded rows per band

// one DPP scan step: x += dpp_shifted(x); out-of-range lanes contribute 0
template <int CTRL, int RMASK>
__device__ __forceinline__ float dpp_add(float x) {
    int t = __builtin_amdgcn_update_dpp(0, __float_as_int(x), CTRL, RMASK, 0xf, true);
    return x + __int_as_float(t);
}

// wave64 inclusive prefix sum, pure VALU (6 dpp-adds)
__device__ __forceinline__ float wave_incl_scan(float x) {
    x = dpp_add<0x111, 0xf>(x);   // row_shr:1
    x = dpp_add<0x112, 0xf>(x);   // row_shr:2
    x = dpp_add<0x114, 0xf>(x);   // row_shr:4
    x = dpp_add<0x118, 0xf>(x);   // row_shr:8
    x = dpp_add<0x142, 0xa>(x);   // row_bcast:15 -> rows 1,3
    x = dpp_add<0x143, 0xc>(x);   // row_bcast:31 -> rows 2,3
    return x;
}

__device__ __forceinline__ float bcast63(float x) {
    return __int_as_float(__builtin_amdgcn_readlane(__float_as_int(x), 63));
}

// Wave-autonomous: each wave owns a 64-col x TY-row strip. No __syncthreads,
// no LDS allocation; cross-lane via DPP scan + ds_bpermute shuffles only.
// NOTE: every __shfl_* MUST be executed unconditionally (full exec mask) —
// shuffles inside a ternary/branch read undefined data from inactive lanes.
__global__ void __launch_bounds__(256)
localnorm_kernel(const float* __restrict__ xin, float* __restrict__ out)
{
    const int tid  = threadIdx.x;
    const int lane = tid & 63;
    const int wv   = tid >> 6;

    const int c0   = blockIdx.x * 256 + wv * 64;  // wave's first output col
    const int row0 = blockIdx.y * TY;
    const int img  = blockIdx.z;

    const float* __restrict__ src = xin + (size_t)img * (H_ * W_);
    float* __restrict__ dst = out + (size_t)img * (H_ * W_) + (size_t)row0 * W_ + c0;

    // padded col -> reflected original col (row-invariant)
    int pcm = c0 - PD_ + lane;                     // main: padded idx = lane
    const int ocm = (pcm < 0) ? -pcm : ((pcm > W_ - 1) ? 2 * (W_ - 1) - pcm : pcm);
    int pct = c0 - PD_ + 64 + lane;                // tail: padded idx = 64+lane (lanes 0..30)
    const int oct = (pct > W_ - 1) ? 2 * (W_ - 1) - pct : pct;
    const bool tl = lane < 31;

    auto rowbase = [&](int p) {
        int r = row0 + p - PD_;
        r = (r < 0) ? -r : ((r > H_ - 1) ? 2 * (H_ - 1) - r : r);
        return src + (size_t)r * W_;
    };

    // 4-deep register prefetch ring for row loads
    float gr[4], gtr[4];
#pragma unroll
    for (int p = 0; p < 4; ++p) {
        const float* rp = rowbase(p);
        gr[p]  = rp[ocm];
        gtr[p] = tl ? rp[oct] : 0.f;
    }

    // 32-deep rolling history of horizontal sums (registers, static idx)
    float histg[32], histq[32];
#pragma unroll
    for (int k = 0; k < 32; ++k) { histg[k] = 0.f; histq[k] = 0.f; }
    float xh[16];                                  // x-center ring (16 rows)
    float vg = 0.f, vq = 0.f;                      // vertical rolling sums

    auto step = [&](int p, int gslot, int hslot, int xslot, int oslot,
                    bool doOut, int i) {
        float g = gr[gslot], gt = gtr[gslot];
        {   // prefetch row p+4 into the slot just freed (clamped; dup loads hit L1)
            int pn = p + 4; if (pn > NROWS - 1) pn = NROWS - 1;
            const float* rp = rowbase(pn);
            gr[gslot]  = rp[ocm];
            gtr[gslot] = tl ? rp[oct] : 0.f;
        }
        float q = g * g, qt = gt * gt;

        // inclusive scans: main (64 vals) and tail (31 vals in lanes 0..30)
        float sag = wave_incl_scan(g);
        float saq = wave_incl_scan(q);
        float sbg = wave_incl_scan(gt);
        float sbq = wave_incl_scan(qt);

        // hsum[lane] = S[lane+31] - S[lane-1] over the 95 padded values
        // (all shuffles hoisted: executed under full exec, selected after)
        float sa63g = bcast63(sag), sa63q = bcast63(saq);
        float dng = __shfl_down(sag, 31);          // S[lane+31], lanes <= 32
        float dnq = __shfl_down(saq, 31);
        float ubg = __shfl_up(sbg, 33);            // SB[lane-33], lanes >= 33
        float ubq = __shfl_up(sbq, 33);
        float slog = sag - g, sloq = saq - q;      // S[lane-1] == exclusive scan
        float shig = (lane <= 32) ? dng : (sa63g + ubg);
        float shiq = (lane <= 32) ? dnq : (sa63q + ubq);
        float hg = shig - slog;
        float hq = shiq - sloq;

        // vertical rolling 32-row window
        vg += hg - histg[hslot]; histg[hslot] = hg;
        vq += hq - histq[hslot]; histq[hslot] = hq;

        // x value at this padded row's center cols (needed 15 steps later).
        // BOTH shuffles unconditional, then select (divergent-shuffle fix).
        float xa = __shfl_down(g, 16);             // padded col lane+16, lanes < 48
        float xb = __shfl_up(gt, 48);              // padded col lane+16, lanes >= 48
        float xc = (lane < 48) ? xa : xb;

        if (doOut) {
            float xv = xh[oslot];                  // x of padded row p-15
            float mg = vg * (1.f / 1024.f);
            float mq = vq * (1.f / 1024.f);
            float sd = sqrtf(fabsf(mq - mg * mg)) + 1e-10f;
            float r  = __fdividef(xv - mg, sd);
            r = fminf(fmaxf(r, -6.f), 6.f);
            dst[(size_t)i * W_ + lane] = r;
        }
        xh[xslot] = xc;
    };

    // prologue: padded rows 0..30 (fills vertical window + x ring)
#pragma unroll
    for (int p = 0; p < 31; ++p)
        step(p, p & 3, p & 31, p & 15, (p + 1) & 15, false, 0);

    // main: padded rows 31..158 -> output rows 0..127
    for (int pb = 31; pb < NROWS; pb += 32) {      // pb = 31,63,95,127 (pb % 32 == 31)
#pragma unroll
        for (int k = 0; k < 32; ++k) {
            step(pb + k, (k + 3) & 3, (k + 31) & 31, (k + 15) & 15, k & 15,
                 true, pb + k - 31);
        }
    }
}

extern "C" void kernel_launch(void* const* d_in, const int* in_sizes, int n_in,
                              void* d_out, int out_size, void* d_ws, size_t ws_size,
                              hipStream_t stream) {
    (void)in_sizes; (void)n_in; (void)d_ws; (void)ws_size; (void)out_size;
    const float* x = (const float*)d_in[0];
    float* o = (float*)d_out;
    dim3 grid(W_ / 256, H_ / TY, NIMG);   // 2 x 4 x 96 = 768 blocks, 3/CU
    localnorm_kernel<<<grid, dim3(256), 0, stream>>>(x, o);
}